// Round 7
// baseline (193.551 us; speedup 1.0000x reference)
//
#include <hip/hip_runtime.h>

// Problem constants (fixed by harness)
#define NPG 96                  // nodes per graph
#define BGR 64                  // graphs
#define HID 64
#define INF 32
#define EF  16
#define DEG 8
#define NN  (BGR*NPG)           // 6144 nodes
#define NE  (BGR*NPG*DEG)       // 49152 edges
#define EPG (NPG*DEG)           // 768 edges per graph
#define PPG (NPG*NPG)           // 9216 pairs per graph

typedef short bf16x8 __attribute__((ext_vector_type(8)));
typedef float f32x4  __attribute__((ext_vector_type(4)));

__device__ __forceinline__ unsigned rne2(float lo, float hi) {
    union { float f; unsigned u; } a, b; a.f = lo; b.f = hi;
    unsigned ua = a.u + 0x7FFF + ((a.u >> 16) & 1);
    unsigned ub = b.u + 0x7FFF + ((b.u >> 16) & 1);
    return (ua >> 16) | (ub & 0xFFFF0000u);
}
__device__ __forceinline__ unsigned short rne1(float x) {
    union { float f; unsigned u; } a; a.f = x;
    return (unsigned short)((a.u + 0x7FFF + ((a.u >> 16) & 1)) >> 16);
}

// ---------------------------------------------------------------------------
// K1: per-node chain:
//   A[n] = ((x@Wa+ba)@Wn+bn)@W1[0:64] + b1,   B[n] = same @ W1[64:128]
// One node per wave; lane = channel.
// ---------------------------------------------------------------------------
__global__ __launch_bounds__(256) void node_kernel(
    const float* __restrict__ x,
    const float* __restrict__ W_atom, const float* __restrict__ b_atom,
    const float* __restrict__ W_node, const float* __restrict__ b_node,
    const float* __restrict__ W1,     const float* __restrict__ b1,
    float* __restrict__ Abuf, float* __restrict__ Bbuf)
{
    __shared__ float sh[4][64];
    const int wave = threadIdx.x >> 6, lane = threadIdx.x & 63;
    const int n = __builtin_amdgcn_readfirstlane(blockIdx.x * 4 + wave);
    const float* xr = x + n * INF;

    float xh = b_atom[lane];
    #pragma unroll
    for (int k = 0; k < INF; ++k) xh += xr[k] * W_atom[k*HID + lane];
    sh[wave][lane] = xh;
    __syncthreads();

    float en = b_node[lane];
    #pragma unroll
    for (int k = 0; k < HID; ++k) en += sh[wave][k] * W_node[k*HID + lane];
    __syncthreads();
    sh[wave][lane] = en;
    __syncthreads();

    float a = b1[lane], b = 0.f;
    #pragma unroll
    for (int k = 0; k < HID; ++k) {
        const float ek = sh[wave][k];
        a += ek * W1[k*HID + lane];
        b += ek * W1[(HID + k)*HID + lane];
    }
    Abuf[n*HID + lane] = a;
    Bbuf[n*HID + lane] = b;
}

// ---------------------------------------------------------------------------
// K2: dense pair MLP on MFMA (unchanged).
// ---------------------------------------------------------------------------
#define SBST 68                 // sB row stride (floats)
#define W2ST 72                 // sW2t row stride (ushorts)
__global__ __launch_bounds__(256) void pair_dense_kernel(
    const float* __restrict__ Abuf, const float* __restrict__ Bbuf,
    const float* __restrict__ W2,   const float* __restrict__ b2,
    const float* __restrict__ W3,   const float* __restrict__ b3,
    float* __restrict__ out)
{
    __shared__ float sB[NPG * SBST];              // 26112 B
    __shared__ float sA[8 * 64];                  //  2048 B
    __shared__ unsigned short sW2t[64 * W2ST];    //  9216 B  (W2^T in bf16)
    const int t  = threadIdx.x;
    const int g  = blockIdx.x / 12;
    const int i0 = (blockIdx.x % 12) * 8;

    const float* Bg = Bbuf + g * NPG * 64;
    for (int idx = t; idx < NPG*64; idx += 256)
        sB[(idx >> 6)*SBST + (idx & 63)] = Bg[idx];
    for (int idx = t; idx < 8*64; idx += 256)
        sA[idx] = Abuf[(g*NPG + i0 + (idx >> 6))*64 + (idx & 63)];
    for (int idx = t; idx < 64*64; idx += 256) {
        const int k = idx >> 6, n = idx & 63;
        sW2t[n*W2ST + k] = rne1(W2[idx]);     // transpose: [n][k]
    }
    __syncthreads();

    const int wave = t >> 6, lane = t & 63;
    const int col = lane & 15, q = lane >> 4;

    bf16x8 w2f[4][2];
    #pragma unroll
    for (int nt = 0; nt < 4; ++nt)
        #pragma unroll
        for (int c = 0; c < 2; ++c)
            w2f[nt][c] = *(const bf16x8*)(sW2t + (nt*16 + col)*W2ST + c*32 + q*8);

    float w3l[4], b2l[4];
    #pragma unroll
    for (int nt = 0; nt < 4; ++nt) {
        w3l[nt] = W3[nt*16 + col];
        b2l[nt] = b2[nt*16 + col];
    }
    const float b3v = b3[0];

    #pragma unroll
    for (int ii = 0; ii < 2; ++ii) {
        const int il = wave*2 + ii;
        float areg[16];
        {
            const float4* Ar = (const float4*)(sA + il*64 + q*8);
            const float4 a0 = Ar[0], a1 = Ar[1];
            const float4 a2 = Ar[8], a3 = Ar[9];
            areg[0]=a0.x; areg[1]=a0.y; areg[2]=a0.z; areg[3]=a0.w;
            areg[4]=a1.x; areg[5]=a1.y; areg[6]=a1.z; areg[7]=a1.w;
            areg[8]=a2.x; areg[9]=a2.y; areg[10]=a2.z; areg[11]=a2.w;
            areg[12]=a3.x; areg[13]=a3.y; areg[14]=a3.z; areg[15]=a3.w;
        }
        float* outr = out + g*PPG + (i0 + il)*NPG;

        for (int jc = 0; jc < 6; ++jc) {
            const int j0 = jc * 16;
            union { bf16x8 v; unsigned u[4]; } h1[2];
            const float* Brow = sB + (j0 + col)*SBST + q*8;
            #pragma unroll
            for (int c = 0; c < 2; ++c) {
                const float4 b0 = *(const float4*)(Brow + c*32);
                const float4 b1v = *(const float4*)(Brow + c*32 + 4);
                float h[8];
                h[0] = fmaxf(areg[c*8+0] + b0.x, 0.f);
                h[1] = fmaxf(areg[c*8+1] + b0.y, 0.f);
                h[2] = fmaxf(areg[c*8+2] + b0.z, 0.f);
                h[3] = fmaxf(areg[c*8+3] + b0.w, 0.f);
                h[4] = fmaxf(areg[c*8+4] + b1v.x, 0.f);
                h[5] = fmaxf(areg[c*8+5] + b1v.y, 0.f);
                h[6] = fmaxf(areg[c*8+6] + b1v.z, 0.f);
                h[7] = fmaxf(areg[c*8+7] + b1v.w, 0.f);
                #pragma unroll
                for (int p2 = 0; p2 < 4; ++p2)
                    h1[c].u[p2] = rne2(h[2*p2], h[2*p2+1]);
            }
            f32x4 acc[4];
            #pragma unroll
            for (int nt = 0; nt < 4; ++nt) {
                f32x4 z = {0.f, 0.f, 0.f, 0.f};
                z = __builtin_amdgcn_mfma_f32_16x16x32_bf16(h1[0].v, w2f[nt][0], z, 0, 0, 0);
                z = __builtin_amdgcn_mfma_f32_16x16x32_bf16(h1[1].v, w2f[nt][1], z, 0, 0, 0);
                acc[nt] = z;
            }
            float p[4];
            #pragma unroll
            for (int r = 0; r < 4; ++r) {
                float s = 0.f;
                #pragma unroll
                for (int nt = 0; nt < 4; ++nt)
                    s += fmaxf(acc[nt][r] + b2l[nt], 0.f) * w3l[nt];
                p[r] = s;
            }
            #pragma unroll
            for (int off = 1; off < 16; off <<= 1) {
                #pragma unroll
                for (int r = 0; r < 4; ++r)
                    p[r] += __shfl_xor(p[r], off, 64);
            }
            if (col == 0) {
                float4 o = make_float4(p[0]+b3v, p[1]+b3v, p[2]+b3v, p[3]+b3v);
                *(float4*)(outr + j0 + q*4) = o;
            }
        }
    }
}

// ---------------------------------------------------------------------------
// K3: dedup edges per graph. One block/graph, one thread/edge. Chain owner
// sums raw edge_attr from L2 (linearity) and emits {key, cnt, sum_ea[16]}.
// Block 0 additionally folds WEc = W_bond@W_edge@W1[128:192] and biasc.
// ---------------------------------------------------------------------------
__global__ __launch_bounds__(EPG) void dedup_kernel(
    const float* __restrict__ ea,  const int* __restrict__ eidx,
    const float* __restrict__ W_bond, const float* __restrict__ b_bond,
    const float* __restrict__ W_edge, const float* __restrict__ b_edge,
    const float* __restrict__ W1,
    int* __restrict__ fkey, int* __restrict__ fcnt,
    float* __restrict__ fsea, int* __restrict__ gcount,
    float* __restrict__ wec, float* __restrict__ biascg)
{
    __shared__ int   head[PPG];        // 36864 B
    __shared__ int   nxt[EPG];         //  3072 B
    __shared__ float sU[16*64];        //  4096 B (fold scratch, block 0 only)
    __shared__ float sbe[64];
    __shared__ int   lcnt;
    const int t = threadIdx.x;
    const int g = blockIdx.x;

    for (int idx = t; idx < PPG; idx += EPG) head[idx] = -1;
    if (t == 0) lcnt = 0;

    const int u = eidx[g*EPG + t]      - g*NPG;
    const int v = eidx[NE + g*EPG + t] - g*NPG;
    const int key = u*NPG + v;
    __syncthreads();

    nxt[t] = atomicExch(&head[key], t);
    __syncthreads();

    if (head[key] == t) {
        const float* eag = ea + (size_t)g * EPG * EF;
        float s[EF];
        #pragma unroll
        for (int q = 0; q < EF; ++q) s[q] = 0.f;
        int cnt = 0;
        for (int e = t; e != -1; e = nxt[e]) {
            ++cnt;
            const float4* p = (const float4*)(eag + e*EF);
            #pragma unroll
            for (int q4 = 0; q4 < 4; ++q4) {
                const float4 f = p[q4];
                s[q4*4+0] += f.x; s[q4*4+1] += f.y;
                s[q4*4+2] += f.z; s[q4*4+3] += f.w;
            }
        }
        const int pos  = atomicAdd(&lcnt, 1);
        const int slot = g*EPG + pos;
        fkey[slot] = key;
        fcnt[slot] = cnt;
        #pragma unroll
        for (int q = 0; q < EF; ++q) fsea[slot*EF + q] = s[q];
    }
    __syncthreads();
    if (t == 0) gcount[g] = lcnt;

    // ---- block 0: fold WEc/biasc (other blocks keep the GPU busy) ----
    if (g == 0) {
        for (int idx = t; idx < 16*64; idx += EPG) {
            const int r = idx >> 6, c = idx & 63;
            float s = 0.f;
            for (int k = 0; k < 64; ++k) s += W_bond[r*64+k] * W_edge[k*64+c];
            sU[idx] = s;
        }
        if (t < 64) {
            float s2 = b_edge[t];
            for (int k = 0; k < 64; ++k) s2 += b_bond[k] * W_edge[k*64+t];
            sbe[t] = s2;
        }
        __syncthreads();
        for (int idx = t; idx < 16*64; idx += EPG) {
            const int r = idx >> 6, c = idx & 63;
            float s = 0.f;
            for (int k = 0; k < 64; ++k) s += sU[r*64+k] * W1[(128+k)*64+c];
            wec[idx] = s;
        }
        if (t < 64) {
            float sc = 0.f;
            for (int k = 0; k < 64; ++k) sc += sbe[k] * W1[(128+k)*64+t];
            biascg[t] = sc;
        }
    }
}

// ---------------------------------------------------------------------------
// K4: fp32 re-run of the MLP for distinct edge-pairs, wave-per-slot.
// Lane = channel; h1[lane] scalar per lane (coalesced A/B reads);
// K-contraction via shfl broadcast + LDS-staged W2; shfl_xor reduce.
// 16 slots/block -> BGR*EPG/16 = 3072 blocks (12/CU).
// ---------------------------------------------------------------------------
#define SLOTS_PER_WAVE 4
#define FIX_BLOCKS ((BGR*EPG)/(4*SLOTS_PER_WAVE))   // 3072
__global__ __launch_bounds__(256) void fixmlp_kernel(
    const float* __restrict__ Abuf, const float* __restrict__ Bbuf,
    const int* __restrict__ fkey, const int* __restrict__ fcnt,
    const float* __restrict__ fsea, const int* __restrict__ gcount,
    const float* __restrict__ wec,  const float* __restrict__ biascg,
    const float* __restrict__ W2,   const float* __restrict__ b2,
    const float* __restrict__ W3,   const float* __restrict__ b3,
    float* __restrict__ out)
{
    __shared__ float sW2[64*64];     // 16384 B
    __shared__ float sWEc[16*64];    //  4096 B
    __shared__ float sbc[64], sb2[64];
    const int t = threadIdx.x;

    for (int idx = t; idx < 64*64; idx += 256) sW2[idx] = W2[idx];
    for (int idx = t; idx < 16*64; idx += 256) sWEc[idx] = wec[idx];
    if (t < 64) { sbc[t] = biascg[t]; sb2[t] = b2[t]; }
    __syncthreads();

    const int wave = t >> 6, lane = t & 63;
    const int s0 = __builtin_amdgcn_readfirstlane(
                       (blockIdx.x * 4 + wave) * SLOTS_PER_WAVE);
    const float b3v = b3[0];
    const float w3l = W3[lane];

    #pragma unroll
    for (int r = 0; r < SLOTS_PER_WAVE; ++r) {
        const int s = s0 + r;
        const int g = s / EPG;
        const int l = s % EPG;
        if (l >= gcount[g]) continue;

        const int key = fkey[s];
        const float cntf = (float)fcnt[s];
        const int u = key / NPG, v = key % NPG;

        float ck = cntf * sbc[lane];
        const float* sep = fsea + (size_t)s * EF;
        #pragma unroll
        for (int q = 0; q < EF; ++q) ck += sep[q] * sWEc[q*64 + lane];

        float h1 = Abuf[(g*NPG + u)*64 + lane] + Bbuf[(g*NPG + v)*64 + lane] + ck;
        h1 = fmaxf(h1, 0.f);

        float h2 = sb2[lane];
        #pragma unroll
        for (int k = 0; k < 64; ++k)
            h2 += __shfl(h1, k, 64) * sW2[k*64 + lane];

        float p = fmaxf(h2, 0.f) * w3l;
        #pragma unroll
        for (int off = 32; off >= 1; off >>= 1)
            p += __shfl_xor(p, off, 64);
        if (lane == 0) out[g*PPG + key] = p + b3v;
    }
}

// ---------------------------------------------------------------------------
extern "C" void kernel_launch(void* const* d_in, const int* in_sizes, int n_in,
                              void* d_out, int out_size, void* d_ws, size_t ws_size,
                              hipStream_t stream)
{
    const float* x      = (const float*)d_in[0];
    const float* ea     = (const float*)d_in[1];
    const int*   eidx   = (const int*)  d_in[2];
    // d_in[3]=idx0, d_in[4]=idx1, d_in[5]=n  -- derivable, unused
    const float* W_atom = (const float*)d_in[6];
    const float* b_atom = (const float*)d_in[7];
    const float* W_bond = (const float*)d_in[8];
    const float* b_bond = (const float*)d_in[9];
    const float* W_node = (const float*)d_in[10];
    const float* b_node = (const float*)d_in[11];
    const float* W_edge = (const float*)d_in[12];
    const float* b_edge = (const float*)d_in[13];
    const float* W1     = (const float*)d_in[14];
    const float* b1     = (const float*)d_in[15];
    const float* W2     = (const float*)d_in[16];
    const float* b2     = (const float*)d_in[17];
    const float* W3     = (const float*)d_in[18];
    const float* b3     = (const float*)d_in[19];
    float* out = (float*)d_out;

    float* ws    = (float*)d_ws;
    float* Abuf  = ws;                       // [NN,64]
    float* Bbuf  = Abuf  + NN*HID;           // [NN,64]
    float* fsea  = Bbuf  + NN*HID;           // [NE,16]
    int*   fkey  = (int*)(fsea + NE*EF);     // [NE]
    int*   fcnt  = fkey + NE;                // [NE]
    int*   gcount= fcnt + NE;                // [BGR]
    float* wec   = (float*)(gcount + BGR);   // [16,64]
    float* biascg= wec + 16*64;              // [64]

    node_kernel<<<NN/4, 256, 0, stream>>>(x, W_atom, b_atom, W_node, b_node,
                                          W1, b1, Abuf, Bbuf);
    dedup_kernel<<<BGR, EPG, 0, stream>>>(ea, eidx, W_bond, b_bond,
                                          W_edge, b_edge, W1,
                                          fkey, fcnt, fsea, gcount,
                                          wec, biascg);
    pair_dense_kernel<<<BGR*12, 256, 0, stream>>>(Abuf, Bbuf,
                                                  W2, b2, W3, b3, out);
    fixmlp_kernel<<<FIX_BLOCKS, 256, 0, stream>>>(
        Abuf, Bbuf, fkey, fcnt, fsea, gcount, wec, biascg,
        W2, b2, W3, b3, out);
}

// Round 8
// 152.948 us; speedup vs baseline: 1.2655x; 1.2655x over previous
//
#include <hip/hip_runtime.h>

// Problem constants (fixed by harness)
#define NPG 96                  // nodes per graph
#define BGR 64                  // graphs
#define HID 64
#define INF 32
#define EF  16
#define DEG 8
#define NN  (BGR*NPG)           // 6144 nodes
#define NE  (BGR*NPG*DEG)       // 49152 edges
#define EPG (NPG*DEG)           // 768 edges per graph
#define PPG (NPG*NPG)           // 9216 pairs per graph

typedef short bf16x8 __attribute__((ext_vector_type(8)));
typedef float f32x4  __attribute__((ext_vector_type(4)));

__device__ __forceinline__ unsigned rne2(float lo, float hi) {
    union { float f; unsigned u; } a, b; a.f = lo; b.f = hi;
    unsigned ua = a.u + 0x7FFF + ((a.u >> 16) & 1);
    unsigned ub = b.u + 0x7FFF + ((b.u >> 16) & 1);
    return (ua >> 16) | (ub & 0xFFFF0000u);
}
__device__ __forceinline__ unsigned short rne1(float x) {
    union { float f; unsigned u; } a; a.f = x;
    return (unsigned short)((a.u + 0x7FFF + ((a.u >> 16) & 1)) >> 16);
}

// ---------------------------------------------------------------------------
// K1: per-node chain:
//   A[n] = ((x@Wa+ba)@Wn+bn)@W1[0:64] + b1,   B[n] = same @ W1[64:128]
// ---------------------------------------------------------------------------
__global__ __launch_bounds__(256) void node_kernel(
    const float* __restrict__ x,
    const float* __restrict__ W_atom, const float* __restrict__ b_atom,
    const float* __restrict__ W_node, const float* __restrict__ b_node,
    const float* __restrict__ W1,     const float* __restrict__ b1,
    float* __restrict__ Abuf, float* __restrict__ Bbuf)
{
    __shared__ float sh[4][64];
    const int wave = threadIdx.x >> 6, lane = threadIdx.x & 63;
    const int n = __builtin_amdgcn_readfirstlane(blockIdx.x * 4 + wave);
    const float* xr = x + n * INF;

    float xh = b_atom[lane];
    #pragma unroll
    for (int k = 0; k < INF; ++k) xh += xr[k] * W_atom[k*HID + lane];
    sh[wave][lane] = xh;
    __syncthreads();

    float en = b_node[lane];
    #pragma unroll
    for (int k = 0; k < HID; ++k) en += sh[wave][k] * W_node[k*HID + lane];
    __syncthreads();
    sh[wave][lane] = en;
    __syncthreads();

    float a = b1[lane], b = 0.f;
    #pragma unroll
    for (int k = 0; k < HID; ++k) {
        const float ek = sh[wave][k];
        a += ek * W1[k*HID + lane];
        b += ek * W1[(HID + k)*HID + lane];
    }
    Abuf[n*HID + lane] = a;
    Bbuf[n*HID + lane] = b;
}

// ---------------------------------------------------------------------------
// K2: dense pair MLP on MFMA (unchanged).
// ---------------------------------------------------------------------------
#define SBST 68                 // sB row stride (floats)
#define W2ST 72                 // sW2t row stride (ushorts)
__global__ __launch_bounds__(256) void pair_dense_kernel(
    const float* __restrict__ Abuf, const float* __restrict__ Bbuf,
    const float* __restrict__ W2,   const float* __restrict__ b2,
    const float* __restrict__ W3,   const float* __restrict__ b3,
    float* __restrict__ out)
{
    __shared__ float sB[NPG * SBST];              // 26112 B
    __shared__ float sA[8 * 64];                  //  2048 B
    __shared__ unsigned short sW2t[64 * W2ST];    //  9216 B  (W2^T in bf16)
    const int t  = threadIdx.x;
    const int g  = blockIdx.x / 12;
    const int i0 = (blockIdx.x % 12) * 8;

    const float* Bg = Bbuf + g * NPG * 64;
    for (int idx = t; idx < NPG*64; idx += 256)
        sB[(idx >> 6)*SBST + (idx & 63)] = Bg[idx];
    for (int idx = t; idx < 8*64; idx += 256)
        sA[idx] = Abuf[(g*NPG + i0 + (idx >> 6))*64 + (idx & 63)];
    for (int idx = t; idx < 64*64; idx += 256) {
        const int k = idx >> 6, n = idx & 63;
        sW2t[n*W2ST + k] = rne1(W2[idx]);     // transpose: [n][k]
    }
    __syncthreads();

    const int wave = t >> 6, lane = t & 63;
    const int col = lane & 15, q = lane >> 4;

    bf16x8 w2f[4][2];
    #pragma unroll
    for (int nt = 0; nt < 4; ++nt)
        #pragma unroll
        for (int c = 0; c < 2; ++c)
            w2f[nt][c] = *(const bf16x8*)(sW2t + (nt*16 + col)*W2ST + c*32 + q*8);

    float w3l[4], b2l[4];
    #pragma unroll
    for (int nt = 0; nt < 4; ++nt) {
        w3l[nt] = W3[nt*16 + col];
        b2l[nt] = b2[nt*16 + col];
    }
    const float b3v = b3[0];

    #pragma unroll
    for (int ii = 0; ii < 2; ++ii) {
        const int il = wave*2 + ii;
        float areg[16];
        {
            const float4* Ar = (const float4*)(sA + il*64 + q*8);
            const float4 a0 = Ar[0], a1 = Ar[1];
            const float4 a2 = Ar[8], a3 = Ar[9];
            areg[0]=a0.x; areg[1]=a0.y; areg[2]=a0.z; areg[3]=a0.w;
            areg[4]=a1.x; areg[5]=a1.y; areg[6]=a1.z; areg[7]=a1.w;
            areg[8]=a2.x; areg[9]=a2.y; areg[10]=a2.z; areg[11]=a2.w;
            areg[12]=a3.x; areg[13]=a3.y; areg[14]=a3.z; areg[15]=a3.w;
        }
        float* outr = out + g*PPG + (i0 + il)*NPG;

        for (int jc = 0; jc < 6; ++jc) {
            const int j0 = jc * 16;
            union { bf16x8 v; unsigned u[4]; } h1[2];
            const float* Brow = sB + (j0 + col)*SBST + q*8;
            #pragma unroll
            for (int c = 0; c < 2; ++c) {
                const float4 b0 = *(const float4*)(Brow + c*32);
                const float4 b1v = *(const float4*)(Brow + c*32 + 4);
                float h[8];
                h[0] = fmaxf(areg[c*8+0] + b0.x, 0.f);
                h[1] = fmaxf(areg[c*8+1] + b0.y, 0.f);
                h[2] = fmaxf(areg[c*8+2] + b0.z, 0.f);
                h[3] = fmaxf(areg[c*8+3] + b0.w, 0.f);
                h[4] = fmaxf(areg[c*8+4] + b1v.x, 0.f);
                h[5] = fmaxf(areg[c*8+5] + b1v.y, 0.f);
                h[6] = fmaxf(areg[c*8+6] + b1v.z, 0.f);
                h[7] = fmaxf(areg[c*8+7] + b1v.w, 0.f);
                #pragma unroll
                for (int p2 = 0; p2 < 4; ++p2)
                    h1[c].u[p2] = rne2(h[2*p2], h[2*p2+1]);
            }
            f32x4 acc[4];
            #pragma unroll
            for (int nt = 0; nt < 4; ++nt) {
                f32x4 z = {0.f, 0.f, 0.f, 0.f};
                z = __builtin_amdgcn_mfma_f32_16x16x32_bf16(h1[0].v, w2f[nt][0], z, 0, 0, 0);
                z = __builtin_amdgcn_mfma_f32_16x16x32_bf16(h1[1].v, w2f[nt][1], z, 0, 0, 0);
                acc[nt] = z;
            }
            float p[4];
            #pragma unroll
            for (int r = 0; r < 4; ++r) {
                float s = 0.f;
                #pragma unroll
                for (int nt = 0; nt < 4; ++nt)
                    s += fmaxf(acc[nt][r] + b2l[nt], 0.f) * w3l[nt];
                p[r] = s;
            }
            #pragma unroll
            for (int off = 1; off < 16; off <<= 1) {
                #pragma unroll
                for (int r = 0; r < 4; ++r)
                    p[r] += __shfl_xor(p[r], off, 64);
            }
            if (col == 0) {
                float4 o = make_float4(p[0]+b3v, p[1]+b3v, p[2]+b3v, p[3]+b3v);
                *(float4*)(outr + j0 + q*4) = o;
            }
        }
    }
}

// ---------------------------------------------------------------------------
// K3: dedup edges per graph (unchanged). Block 0 folds WEc/biasc.
// ---------------------------------------------------------------------------
__global__ __launch_bounds__(EPG) void dedup_kernel(
    const float* __restrict__ ea,  const int* __restrict__ eidx,
    const float* __restrict__ W_bond, const float* __restrict__ b_bond,
    const float* __restrict__ W_edge, const float* __restrict__ b_edge,
    const float* __restrict__ W1,
    int* __restrict__ fkey, int* __restrict__ fcnt,
    float* __restrict__ fsea, int* __restrict__ gcount,
    float* __restrict__ wec, float* __restrict__ biascg)
{
    __shared__ int   head[PPG];        // 36864 B
    __shared__ int   nxt[EPG];         //  3072 B
    __shared__ float sU[16*64];        //  4096 B (fold scratch, block 0 only)
    __shared__ float sbe[64];
    __shared__ int   lcnt;
    const int t = threadIdx.x;
    const int g = blockIdx.x;

    for (int idx = t; idx < PPG; idx += EPG) head[idx] = -1;
    if (t == 0) lcnt = 0;

    const int u = eidx[g*EPG + t]      - g*NPG;
    const int v = eidx[NE + g*EPG + t] - g*NPG;
    const int key = u*NPG + v;
    __syncthreads();

    nxt[t] = atomicExch(&head[key], t);
    __syncthreads();

    if (head[key] == t) {
        const float* eag = ea + (size_t)g * EPG * EF;
        float s[EF];
        #pragma unroll
        for (int q = 0; q < EF; ++q) s[q] = 0.f;
        int cnt = 0;
        for (int e = t; e != -1; e = nxt[e]) {
            ++cnt;
            const float4* p = (const float4*)(eag + e*EF);
            #pragma unroll
            for (int q4 = 0; q4 < 4; ++q4) {
                const float4 f = p[q4];
                s[q4*4+0] += f.x; s[q4*4+1] += f.y;
                s[q4*4+2] += f.z; s[q4*4+3] += f.w;
            }
        }
        const int pos  = atomicAdd(&lcnt, 1);
        const int slot = g*EPG + pos;
        fkey[slot] = key;
        fcnt[slot] = cnt;
        #pragma unroll
        for (int q = 0; q < EF; ++q) fsea[slot*EF + q] = s[q];
    }
    __syncthreads();
    if (t == 0) gcount[g] = lcnt;

    // ---- block 0: fold WEc/biasc (other blocks keep the GPU busy) ----
    if (g == 0) {
        for (int idx = t; idx < 16*64; idx += EPG) {
            const int r = idx >> 6, c = idx & 63;
            float s = 0.f;
            for (int k = 0; k < 64; ++k) s += W_bond[r*64+k] * W_edge[k*64+c];
            sU[idx] = s;
        }
        if (t < 64) {
            float s2 = b_edge[t];
            for (int k = 0; k < 64; ++k) s2 += b_bond[k] * W_edge[k*64+t];
            sbe[t] = s2;
        }
        __syncthreads();
        for (int idx = t; idx < 16*64; idx += EPG) {
            const int r = idx >> 6, c = idx & 63;
            float s = 0.f;
            for (int k = 0; k < 64; ++k) s += sU[r*64+k] * W1[(128+k)*64+c];
            wec[idx] = s;
        }
        if (t < 64) {
            float sc = 0.f;
            for (int k = 0; k < 64; ++k) sc += sbe[k] * W1[(128+k)*64+t];
            biascg[t] = sc;
        }
    }
}

// ---------------------------------------------------------------------------
// K4: MFMA re-run of the MLP for distinct edge-pairs, 16 slots per wave.
// Lane (col=lane&15, q=lane>>4) builds the A-fragment of slot col directly
// from global Abuf/Bbuf rows (float4 gathers, L2-hot) plus fp32
// ck = cnt*biasc + se@WEc (WEc in LDS, quad-broadcast reads), relu+RNE-pack,
// then 8 mfma_f32_16x16x32_bf16 against the same bf16 W2 frags as K2.
// Epilogue identical to K2's shfl_xor reduction; col==0 stores per-slot.
// ---------------------------------------------------------------------------
#define FIXW 16                                  // slots per wave
#define FIX_BLOCKS (NE / (FIXW * 4))             // 768
__global__ __launch_bounds__(256) void fixmlp_kernel(
    const float* __restrict__ Abuf, const float* __restrict__ Bbuf,
    const int* __restrict__ fkey, const int* __restrict__ fcnt,
    const float* __restrict__ fsea, const int* __restrict__ gcount,
    const float* __restrict__ wec,  const float* __restrict__ biascg,
    const float* __restrict__ W2,   const float* __restrict__ b2,
    const float* __restrict__ W3,   const float* __restrict__ b3,
    float* __restrict__ out)
{
    __shared__ unsigned short sW2t[64 * W2ST];   // 9216 B (W2^T bf16)
    __shared__ float sWEc[16*64];                // 4096 B
    __shared__ float sbc[64];
    const int t = threadIdx.x;

    for (int idx = t; idx < 64*64; idx += 256) {
        const int k = idx >> 6, n = idx & 63;
        sW2t[n*W2ST + k] = rne1(W2[idx]);
    }
    for (int idx = t; idx < 16*64; idx += 256) sWEc[idx] = wec[idx];
    if (t < 64) sbc[t] = biascg[t];
    __syncthreads();

    const int wave = t >> 6, lane = t & 63;
    const int col = lane & 15, q = lane >> 4;
    const int s0 = (blockIdx.x * 4 + wave) * FIXW;   // group base slot
    const int g  = s0 / EPG;
    const int l0 = s0 % EPG;
    const int cg = gcount[g];
    if (l0 >= cg) return;                 // fully-invalid group (wave-uniform)

    bf16x8 w2f[4][2];
    #pragma unroll
    for (int nt = 0; nt < 4; ++nt)
        #pragma unroll
        for (int c = 0; c < 2; ++c)
            w2f[nt][c] = *(const bf16x8*)(sW2t + (nt*16 + col)*W2ST + c*32 + q*8);

    float w3l[4], b2l[4];
    #pragma unroll
    for (int nt = 0; nt < 4; ++nt) {
        w3l[nt] = W3[nt*16 + col];
        b2l[nt] = b2[nt*16 + col];
    }
    const float b3v = b3[0];
    const int k0 = q * 8;                 // this lane's k-chunk base (within 32)

    // ---- build A-fragments for slot (s0+col), k = k0..k0+8 and 32+k0..+8 ----
    union { bf16x8 v; unsigned u[4]; } h1[2];
    #pragma unroll
    for (int p2 = 0; p2 < 4; ++p2) { h1[0].u[p2] = 0; h1[1].u[p2] = 0; }

    const int s = s0 + col;
    if (l0 + col < cg) {
        const int key  = fkey[s];
        const float cf = (float)fcnt[s];
        const int ui = key / NPG, vi = key % NPG;

        float se[16];
        {
            const float4* p = (const float4*)(fsea + (size_t)s * EF);
            #pragma unroll
            for (int q4 = 0; q4 < 4; ++q4) {
                const float4 f = p[q4];
                se[q4*4+0] = f.x; se[q4*4+1] = f.y;
                se[q4*4+2] = f.z; se[q4*4+3] = f.w;
            }
        }

        float ck[16];
        #pragma unroll
        for (int kk = 0; kk < 8; ++kk) {
            ck[kk]     = cf * sbc[k0 + kk];
            ck[8 + kk] = cf * sbc[32 + k0 + kk];
        }
        #pragma unroll
        for (int qq = 0; qq < 16; ++qq) {
            const float sq = se[qq];
            const float4 w0 = *(const float4*)(sWEc + qq*64 + k0);
            const float4 w1 = *(const float4*)(sWEc + qq*64 + k0 + 4);
            const float4 w2v = *(const float4*)(sWEc + qq*64 + k0 + 32);
            const float4 w3v = *(const float4*)(sWEc + qq*64 + k0 + 36);
            ck[0]  += sq * w0.x;  ck[1]  += sq * w0.y;
            ck[2]  += sq * w0.z;  ck[3]  += sq * w0.w;
            ck[4]  += sq * w1.x;  ck[5]  += sq * w1.y;
            ck[6]  += sq * w1.z;  ck[7]  += sq * w1.w;
            ck[8]  += sq * w2v.x; ck[9]  += sq * w2v.y;
            ck[10] += sq * w2v.z; ck[11] += sq * w2v.w;
            ck[12] += sq * w3v.x; ck[13] += sq * w3v.y;
            ck[14] += sq * w3v.z; ck[15] += sq * w3v.w;
        }

        const float* Ar = Abuf + (g*NPG + ui)*64;
        const float* Br = Bbuf + (g*NPG + vi)*64;
        const float4 a0 = *(const float4*)(Ar + k0);
        const float4 a1 = *(const float4*)(Ar + k0 + 4);
        const float4 a2 = *(const float4*)(Ar + k0 + 32);
        const float4 a3 = *(const float4*)(Ar + k0 + 36);
        const float4 c0 = *(const float4*)(Br + k0);
        const float4 c1 = *(const float4*)(Br + k0 + 4);
        const float4 c2 = *(const float4*)(Br + k0 + 32);
        const float4 c3 = *(const float4*)(Br + k0 + 36);

        float h[16];
        h[0]  = fmaxf(a0.x + c0.x + ck[0],  0.f);
        h[1]  = fmaxf(a0.y + c0.y + ck[1],  0.f);
        h[2]  = fmaxf(a0.z + c0.z + ck[2],  0.f);
        h[3]  = fmaxf(a0.w + c0.w + ck[3],  0.f);
        h[4]  = fmaxf(a1.x + c1.x + ck[4],  0.f);
        h[5]  = fmaxf(a1.y + c1.y + ck[5],  0.f);
        h[6]  = fmaxf(a1.z + c1.z + ck[6],  0.f);
        h[7]  = fmaxf(a1.w + c1.w + ck[7],  0.f);
        h[8]  = fmaxf(a2.x + c2.x + ck[8],  0.f);
        h[9]  = fmaxf(a2.y + c2.y + ck[9],  0.f);
        h[10] = fmaxf(a2.z + c2.z + ck[10], 0.f);
        h[11] = fmaxf(a2.w + c2.w + ck[11], 0.f);
        h[12] = fmaxf(a3.x + c3.x + ck[12], 0.f);
        h[13] = fmaxf(a3.y + c3.y + ck[13], 0.f);
        h[14] = fmaxf(a3.z + c3.z + ck[14], 0.f);
        h[15] = fmaxf(a3.w + c3.w + ck[15], 0.f);
        #pragma unroll
        for (int p2 = 0; p2 < 4; ++p2) {
            h1[0].u[p2] = rne2(h[2*p2],     h[2*p2 + 1]);
            h1[1].u[p2] = rne2(h[8 + 2*p2], h[8 + 2*p2 + 1]);
        }
    }

    f32x4 acc[4];
    #pragma unroll
    for (int nt = 0; nt < 4; ++nt) {
        f32x4 z = {0.f, 0.f, 0.f, 0.f};
        z = __builtin_amdgcn_mfma_f32_16x16x32_bf16(h1[0].v, w2f[nt][0], z, 0, 0, 0);
        z = __builtin_amdgcn_mfma_f32_16x16x32_bf16(h1[1].v, w2f[nt][1], z, 0, 0, 0);
        acc[nt] = z;
    }

    float p[4];
    #pragma unroll
    for (int r = 0; r < 4; ++r) {
        float sum = 0.f;
        #pragma unroll
        for (int nt = 0; nt < 4; ++nt)
            sum += fmaxf(acc[nt][r] + b2l[nt], 0.f) * w3l[nt];
        p[r] = sum;
    }
    #pragma unroll
    for (int off = 1; off < 16; off <<= 1) {
        #pragma unroll
        for (int r = 0; r < 4; ++r)
            p[r] += __shfl_xor(p[r], off, 64);
    }
    if (col == 0) {
        #pragma unroll
        for (int r = 0; r < 4; ++r) {
            const int lr = q*4 + r;                // slot-local in group
            if (l0 + lr < cg) {
                const int keyr = fkey[s0 + lr];
                out[g*PPG + keyr] = p[r] + b3v;
            }
        }
    }
}

// ---------------------------------------------------------------------------
extern "C" void kernel_launch(void* const* d_in, const int* in_sizes, int n_in,
                              void* d_out, int out_size, void* d_ws, size_t ws_size,
                              hipStream_t stream)
{
    const float* x      = (const float*)d_in[0];
    const float* ea     = (const float*)d_in[1];
    const int*   eidx   = (const int*)  d_in[2];
    // d_in[3]=idx0, d_in[4]=idx1, d_in[5]=n  -- derivable, unused
    const float* W_atom = (const float*)d_in[6];
    const float* b_atom = (const float*)d_in[7];
    const float* W_bond = (const float*)d_in[8];
    const float* b_bond = (const float*)d_in[9];
    const float* W_node = (const float*)d_in[10];
    const float* b_node = (const float*)d_in[11];
    const float* W_edge = (const float*)d_in[12];
    const float* b_edge = (const float*)d_in[13];
    const float* W1     = (const float*)d_in[14];
    const float* b1     = (const float*)d_in[15];
    const float* W2     = (const float*)d_in[16];
    const float* b2     = (const float*)d_in[17];
    const float* W3     = (const float*)d_in[18];
    const float* b3     = (const float*)d_in[19];
    float* out = (float*)d_out;

    float* ws    = (float*)d_ws;
    float* Abuf  = ws;                       // [NN,64]
    float* Bbuf  = Abuf  + NN*HID;           // [NN,64]
    float* fsea  = Bbuf  + NN*HID;           // [NE,16]
    int*   fkey  = (int*)(fsea + NE*EF);     // [NE]
    int*   fcnt  = fkey + NE;                // [NE]
    int*   gcount= fcnt + NE;                // [BGR]
    float* wec   = (float*)(gcount + BGR);   // [16,64]
    float* biascg= wec + 16*64;              // [64]

    node_kernel<<<NN/4, 256, 0, stream>>>(x, W_atom, b_atom, W_node, b_node,
                                          W1, b1, Abuf, Bbuf);
    dedup_kernel<<<BGR, EPG, 0, stream>>>(ea, eidx, W_bond, b_bond,
                                          W_edge, b_edge, W1,
                                          fkey, fcnt, fsea, gcount,
                                          wec, biascg);
    pair_dense_kernel<<<BGR*12, 256, 0, stream>>>(Abuf, Bbuf,
                                                  W2, b2, W3, b3, out);
    fixmlp_kernel<<<FIX_BLOCKS, 256, 0, stream>>>(
        Abuf, Bbuf, fkey, fcnt, fsea, gcount, wec, biascg,
        W2, b2, W3, b3, out);
}

// Round 9
// 142.409 us; speedup vs baseline: 1.3591x; 1.0740x over previous
//
#include <hip/hip_runtime.h>

// Problem constants (fixed by harness)
#define NPG 96                  // nodes per graph
#define BGR 64                  // graphs
#define HID 64
#define INF 32
#define EF  16
#define DEG 8
#define NN  (BGR*NPG)           // 6144 nodes
#define NE  (BGR*NPG*DEG)       // 49152 edges
#define EPG (NPG*DEG)           // 768 edges per graph
#define PPG (NPG*NPG)           // 9216 pairs per graph
#define BMW 288                 // bitmap words per graph (9216 bits)

typedef short bf16x8 __attribute__((ext_vector_type(8)));
typedef float f32x4  __attribute__((ext_vector_type(4)));

__device__ __forceinline__ unsigned rne2(float lo, float hi) {
    union { float f; unsigned u; } a, b; a.f = lo; b.f = hi;
    unsigned ua = a.u + 0x7FFF + ((a.u >> 16) & 1);
    unsigned ub = b.u + 0x7FFF + ((b.u >> 16) & 1);
    return (ua >> 16) | (ub & 0xFFFF0000u);
}
__device__ __forceinline__ unsigned short rne1(float x) {
    union { float f; unsigned u; } a; a.f = x;
    return (unsigned short)((a.u + 0x7FFF + ((a.u >> 16) & 1)) >> 16);
}

// ---------------------------------------------------------------------------
// K1 "prep": blocks 0..63 = per-graph edge dedup (+ edge bitmap; block 0 also
// folds WEc/biasc). Blocks 64..575 = node chain, 12 nodes/block (1/wave).
// Merging the two independent kernels overlaps them instead of serializing.
// ---------------------------------------------------------------------------
__global__ __launch_bounds__(768) void prep_kernel(
    const float* __restrict__ x,
    const float* __restrict__ W_atom, const float* __restrict__ b_atom,
    const float* __restrict__ W_node, const float* __restrict__ b_node,
    const float* __restrict__ W1,     const float* __restrict__ b1,
    const float* __restrict__ ea,     const int* __restrict__ eidx,
    const float* __restrict__ W_bond, const float* __restrict__ b_bond,
    const float* __restrict__ W_edge, const float* __restrict__ b_edge,
    float* __restrict__ Abuf, float* __restrict__ Bbuf,
    int* __restrict__ fkey, int* __restrict__ fcnt,
    float* __restrict__ fsea, int* __restrict__ gcount,
    float* __restrict__ wec, float* __restrict__ biascg,
    unsigned* __restrict__ gbm)
{
    __shared__ __align__(16) char smem[45504];
    const int t = threadIdx.x;

    if (blockIdx.x >= 64) {
        // ---------------- node path: 12 nodes per block ----------------
        float* sh = (float*)smem;               // [12][64]
        const int wave = t >> 6, lane = t & 63;
        const int n = __builtin_amdgcn_readfirstlane((blockIdx.x - 64)*12 + wave);
        const float* xr = x + n * INF;

        float xh = b_atom[lane];
        #pragma unroll
        for (int k = 0; k < INF; ++k) xh += xr[k] * W_atom[k*HID + lane];
        sh[wave*64 + lane] = xh;
        __syncthreads();

        float en = b_node[lane];
        #pragma unroll
        for (int k = 0; k < HID; ++k) en += sh[wave*64 + k] * W_node[k*HID + lane];
        __syncthreads();
        sh[wave*64 + lane] = en;
        __syncthreads();

        float a = b1[lane], b = 0.f;
        #pragma unroll
        for (int k = 0; k < HID; ++k) {
            const float ek = sh[wave*64 + k];
            a += ek * W1[k*HID + lane];
            b += ek * W1[(HID + k)*HID + lane];
        }
        Abuf[n*HID + lane] = a;
        Bbuf[n*HID + lane] = b;
        return;
    }

    // ---------------- dedup path: one graph per block ----------------
    int*      head = (int*)smem;                          // 36864
    int*      nxt  = (int*)(smem + 36864);                //  3072
    float*    sU   = (float*)(smem + 36864 + 3072);       //  4096
    float*    sbe  = (float*)(smem + 36864 + 3072 + 4096);//   256
    unsigned* bm   = (unsigned*)(smem + 36864+3072+4096+256); // 1152
    int*      lcnt = (int*)(smem + 36864+3072+4096+256+1152);
    const int g = blockIdx.x;

    for (int idx = t; idx < PPG; idx += EPG) head[idx] = -1;
    for (int idx = t; idx < BMW; idx += EPG) bm[idx] = 0u;
    if (t == 0) *lcnt = 0;

    const int u = eidx[g*EPG + t]      - g*NPG;
    const int v = eidx[NE + g*EPG + t] - g*NPG;
    const int key = u*NPG + v;
    __syncthreads();

    nxt[t] = atomicExch(&head[key], t);
    __syncthreads();

    if (head[key] == t) {
        const float* eag = ea + (size_t)g * EPG * EF;
        float s[EF];
        #pragma unroll
        for (int q = 0; q < EF; ++q) s[q] = 0.f;
        int cnt = 0;
        for (int e = t; e != -1; e = nxt[e]) {
            ++cnt;
            const float4* p = (const float4*)(eag + e*EF);
            #pragma unroll
            for (int q4 = 0; q4 < 4; ++q4) {
                const float4 f = p[q4];
                s[q4*4+0] += f.x; s[q4*4+1] += f.y;
                s[q4*4+2] += f.z; s[q4*4+3] += f.w;
            }
        }
        atomicOr(&bm[key >> 5], 1u << (key & 31));
        const int pos  = atomicAdd(lcnt, 1);
        const int slot = g*EPG + pos;
        fkey[slot] = key;
        fcnt[slot] = cnt;
        #pragma unroll
        for (int q = 0; q < EF; ++q) fsea[slot*EF + q] = s[q];
    }
    __syncthreads();
    for (int idx = t; idx < BMW; idx += EPG) gbm[g*BMW + idx] = bm[idx];
    if (t == 0) gcount[g] = *lcnt;

    // ---- block 0: fold WEc = W_bond@W_edge@W1c, biasc ----
    if (g == 0) {
        for (int idx = t; idx < 16*64; idx += EPG) {
            const int r = idx >> 6, c = idx & 63;
            float s = 0.f;
            for (int k = 0; k < 64; ++k) s += W_bond[r*64+k] * W_edge[k*64+c];
            sU[idx] = s;
        }
        if (t < 64) {
            float s2 = b_edge[t];
            for (int k = 0; k < 64; ++k) s2 += b_bond[k] * W_edge[k*64+t];
            sbe[t] = s2;
        }
        __syncthreads();
        for (int idx = t; idx < 16*64; idx += EPG) {
            const int r = idx >> 6, c = idx & 63;
            float s = 0.f;
            for (int k = 0; k < 64; ++k) s += sU[r*64+k] * W1[(128+k)*64+c];
            wec[idx] = s;
        }
        if (t < 64) {
            float sc = 0.f;
            for (int k = 0; k < 64; ++k) sc += sbe[k] * W1[(128+k)*64+t];
            biascg[t] = sc;
        }
    }
}

// ---------------------------------------------------------------------------
// K2 "pair": blocks 0..767 = dense MFMA pair MLP, but SKIP stores for pairs
// with >=1 edge (bitmap-predicated scalar stores). Blocks 768..1535 = MFMA
// edge-pair MLP with sparse term; writes exactly the masked keys. Write sets
// are disjoint, so both halves run concurrently in one dispatch.
// ---------------------------------------------------------------------------
#define SBST 68                 // sB row stride (floats)
#define W2ST 72                 // sW2t row stride (ushorts)
#define FIXW 16                 // slots per wave (fix half)
__global__ __launch_bounds__(256) void pair_kernel(
    const float* __restrict__ Abuf, const float* __restrict__ Bbuf,
    const int* __restrict__ fkey, const int* __restrict__ fcnt,
    const float* __restrict__ fsea, const int* __restrict__ gcount,
    const float* __restrict__ wec,  const float* __restrict__ biascg,
    const unsigned* __restrict__ gbm,
    const float* __restrict__ W2,   const float* __restrict__ b2,
    const float* __restrict__ W3,   const float* __restrict__ b3,
    float* __restrict__ out)
{
    __shared__ __align__(16) char smem[37504];
    const int t = threadIdx.x;
    const int wave = t >> 6, lane = t & 63;
    const int col = lane & 15, q = lane >> 4;
    const float b3v = b3[0];

    if (blockIdx.x < 768) {
        // ================= dense half =================
        float*          sB   = (float*)smem;                    // 26112
        float*          sA   = (float*)(smem + 26112);          //  2048
        unsigned short* sW2t = (unsigned short*)(smem + 28160); //  9216
        unsigned*       sBM  = (unsigned*)(smem + 28160 + 9216);//    96
        const int g  = blockIdx.x / 12;
        const int i0 = (blockIdx.x % 12) * 8;

        const float* Bg = Bbuf + g * NPG * 64;
        for (int idx = t; idx < NPG*64; idx += 256)
            sB[(idx >> 6)*SBST + (idx & 63)] = Bg[idx];
        for (int idx = t; idx < 8*64; idx += 256)
            sA[idx] = Abuf[(g*NPG + i0 + (idx >> 6))*64 + (idx & 63)];
        for (int idx = t; idx < 64*64; idx += 256) {
            const int k = idx >> 6, n = idx & 63;
            sW2t[n*W2ST + k] = rne1(W2[idx]);
        }
        if (t < 24) sBM[t] = gbm[g*BMW + i0*3 + t];
        __syncthreads();

        bf16x8 w2f[4][2];
        #pragma unroll
        for (int nt = 0; nt < 4; ++nt)
            #pragma unroll
            for (int c = 0; c < 2; ++c)
                w2f[nt][c] = *(const bf16x8*)(sW2t + (nt*16 + col)*W2ST + c*32 + q*8);

        float w3l[4], b2l[4];
        #pragma unroll
        for (int nt = 0; nt < 4; ++nt) {
            w3l[nt] = W3[nt*16 + col];
            b2l[nt] = b2[nt*16 + col];
        }

        #pragma unroll
        for (int ii = 0; ii < 2; ++ii) {
            const int il = wave*2 + ii;
            float areg[16];
            {
                const float4* Ar = (const float4*)(sA + il*64 + q*8);
                const float4 a0 = Ar[0], a1 = Ar[1];
                const float4 a2 = Ar[8], a3 = Ar[9];
                areg[0]=a0.x; areg[1]=a0.y; areg[2]=a0.z; areg[3]=a0.w;
                areg[4]=a1.x; areg[5]=a1.y; areg[6]=a1.z; areg[7]=a1.w;
                areg[8]=a2.x; areg[9]=a2.y; areg[10]=a2.z; areg[11]=a2.w;
                areg[12]=a3.x; areg[13]=a3.y; areg[14]=a3.z; areg[15]=a3.w;
            }
            float* outr = out + g*PPG + (i0 + il)*NPG;

            for (int jc = 0; jc < 6; ++jc) {
                const int j0 = jc * 16;
                union { bf16x8 v; unsigned u[4]; } h1[2];
                const float* Brow = sB + (j0 + col)*SBST + q*8;
                #pragma unroll
                for (int c = 0; c < 2; ++c) {
                    const float4 b0 = *(const float4*)(Brow + c*32);
                    const float4 b1v = *(const float4*)(Brow + c*32 + 4);
                    float h[8];
                    h[0] = fmaxf(areg[c*8+0] + b0.x, 0.f);
                    h[1] = fmaxf(areg[c*8+1] + b0.y, 0.f);
                    h[2] = fmaxf(areg[c*8+2] + b0.z, 0.f);
                    h[3] = fmaxf(areg[c*8+3] + b0.w, 0.f);
                    h[4] = fmaxf(areg[c*8+4] + b1v.x, 0.f);
                    h[5] = fmaxf(areg[c*8+5] + b1v.y, 0.f);
                    h[6] = fmaxf(areg[c*8+6] + b1v.z, 0.f);
                    h[7] = fmaxf(areg[c*8+7] + b1v.w, 0.f);
                    #pragma unroll
                    for (int p2 = 0; p2 < 4; ++p2)
                        h1[c].u[p2] = rne2(h[2*p2], h[2*p2+1]);
                }
                f32x4 acc[4];
                #pragma unroll
                for (int nt = 0; nt < 4; ++nt) {
                    f32x4 z = {0.f, 0.f, 0.f, 0.f};
                    z = __builtin_amdgcn_mfma_f32_16x16x32_bf16(h1[0].v, w2f[nt][0], z, 0, 0, 0);
                    z = __builtin_amdgcn_mfma_f32_16x16x32_bf16(h1[1].v, w2f[nt][1], z, 0, 0, 0);
                    acc[nt] = z;
                }
                float p[4];
                #pragma unroll
                for (int r = 0; r < 4; ++r) {
                    float s = 0.f;
                    #pragma unroll
                    for (int nt = 0; nt < 4; ++nt)
                        s += fmaxf(acc[nt][r] + b2l[nt], 0.f) * w3l[nt];
                    p[r] = s;
                }
                #pragma unroll
                for (int off = 1; off < 16; off <<= 1) {
                    #pragma unroll
                    for (int r = 0; r < 4; ++r)
                        p[r] += __shfl_xor(p[r], off, 64);
                }
                if (col == 0) {
                    #pragma unroll
                    for (int r = 0; r < 4; ++r) {
                        const int j = j0 + q*4 + r;
                        if (!((sBM[il*3 + (j >> 5)] >> (j & 31)) & 1u))
                            outr[j] = p[r] + b3v;
                    }
                }
            }
        }
        return;
    }

    // ================= fix half (edge pairs) =================
    unsigned short* sW2t = (unsigned short*)smem;        // 9216
    float*          sWEc = (float*)(smem + 9216);        // 4096
    float*          sbc  = (float*)(smem + 9216 + 4096); //  256

    for (int idx = t; idx < 64*64; idx += 256) {
        const int k = idx >> 6, n = idx & 63;
        sW2t[n*W2ST + k] = rne1(W2[idx]);
    }
    for (int idx = t; idx < 16*64; idx += 256) sWEc[idx] = wec[idx];
    if (t < 64) sbc[t] = biascg[t];
    __syncthreads();

    const int fb = blockIdx.x - 768;
    const int s0 = (fb * 4 + wave) * FIXW;
    const int g  = s0 / EPG;
    const int l0 = s0 % EPG;
    const int cg = gcount[g];
    if (l0 >= cg) return;

    bf16x8 w2f[4][2];
    #pragma unroll
    for (int nt = 0; nt < 4; ++nt)
        #pragma unroll
        for (int c = 0; c < 2; ++c)
            w2f[nt][c] = *(const bf16x8*)(sW2t + (nt*16 + col)*W2ST + c*32 + q*8);

    float w3l[4], b2l[4];
    #pragma unroll
    for (int nt = 0; nt < 4; ++nt) {
        w3l[nt] = W3[nt*16 + col];
        b2l[nt] = b2[nt*16 + col];
    }
    const int k0 = q * 8;

    union { bf16x8 v; unsigned u[4]; } h1[2];
    #pragma unroll
    for (int p2 = 0; p2 < 4; ++p2) { h1[0].u[p2] = 0; h1[1].u[p2] = 0; }

    const int s = s0 + col;
    if (l0 + col < cg) {
        const int key  = fkey[s];
        const float cf = (float)fcnt[s];
        const int ui = key / NPG, vi = key % NPG;

        float se[16];
        {
            const float4* p = (const float4*)(fsea + (size_t)s * EF);
            #pragma unroll
            for (int q4 = 0; q4 < 4; ++q4) {
                const float4 f = p[q4];
                se[q4*4+0] = f.x; se[q4*4+1] = f.y;
                se[q4*4+2] = f.z; se[q4*4+3] = f.w;
            }
        }

        float ck[16];
        #pragma unroll
        for (int kk = 0; kk < 8; ++kk) {
            ck[kk]     = cf * sbc[k0 + kk];
            ck[8 + kk] = cf * sbc[32 + k0 + kk];
        }
        #pragma unroll
        for (int qq = 0; qq < 16; ++qq) {
            const float sq = se[qq];
            const float4 w0 = *(const float4*)(sWEc + qq*64 + k0);
            const float4 w1 = *(const float4*)(sWEc + qq*64 + k0 + 4);
            const float4 w2v = *(const float4*)(sWEc + qq*64 + k0 + 32);
            const float4 w3v = *(const float4*)(sWEc + qq*64 + k0 + 36);
            ck[0]  += sq * w0.x;  ck[1]  += sq * w0.y;
            ck[2]  += sq * w0.z;  ck[3]  += sq * w0.w;
            ck[4]  += sq * w1.x;  ck[5]  += sq * w1.y;
            ck[6]  += sq * w1.z;  ck[7]  += sq * w1.w;
            ck[8]  += sq * w2v.x; ck[9]  += sq * w2v.y;
            ck[10] += sq * w2v.z; ck[11] += sq * w2v.w;
            ck[12] += sq * w3v.x; ck[13] += sq * w3v.y;
            ck[14] += sq * w3v.z; ck[15] += sq * w3v.w;
        }

        const float* Ar = Abuf + (g*NPG + ui)*64;
        const float* Br = Bbuf + (g*NPG + vi)*64;
        const float4 a0 = *(const float4*)(Ar + k0);
        const float4 a1 = *(const float4*)(Ar + k0 + 4);
        const float4 a2 = *(const float4*)(Ar + k0 + 32);
        const float4 a3 = *(const float4*)(Ar + k0 + 36);
        const float4 c0 = *(const float4*)(Br + k0);
        const float4 c1 = *(const float4*)(Br + k0 + 4);
        const float4 c2 = *(const float4*)(Br + k0 + 32);
        const float4 c3 = *(const float4*)(Br + k0 + 36);

        float h[16];
        h[0]  = fmaxf(a0.x + c0.x + ck[0],  0.f);
        h[1]  = fmaxf(a0.y + c0.y + ck[1],  0.f);
        h[2]  = fmaxf(a0.z + c0.z + ck[2],  0.f);
        h[3]  = fmaxf(a0.w + c0.w + ck[3],  0.f);
        h[4]  = fmaxf(a1.x + c1.x + ck[4],  0.f);
        h[5]  = fmaxf(a1.y + c1.y + ck[5],  0.f);
        h[6]  = fmaxf(a1.z + c1.z + ck[6],  0.f);
        h[7]  = fmaxf(a1.w + c1.w + ck[7],  0.f);
        h[8]  = fmaxf(a2.x + c2.x + ck[8],  0.f);
        h[9]  = fmaxf(a2.y + c2.y + ck[9],  0.f);
        h[10] = fmaxf(a2.z + c2.z + ck[10], 0.f);
        h[11] = fmaxf(a2.w + c2.w + ck[11], 0.f);
        h[12] = fmaxf(a3.x + c3.x + ck[12], 0.f);
        h[13] = fmaxf(a3.y + c3.y + ck[13], 0.f);
        h[14] = fmaxf(a3.z + c3.z + ck[14], 0.f);
        h[15] = fmaxf(a3.w + c3.w + ck[15], 0.f);
        #pragma unroll
        for (int p2 = 0; p2 < 4; ++p2) {
            h1[0].u[p2] = rne2(h[2*p2],     h[2*p2 + 1]);
            h1[1].u[p2] = rne2(h[8 + 2*p2], h[8 + 2*p2 + 1]);
        }
    }

    f32x4 acc[4];
    #pragma unroll
    for (int nt = 0; nt < 4; ++nt) {
        f32x4 z = {0.f, 0.f, 0.f, 0.f};
        z = __builtin_amdgcn_mfma_f32_16x16x32_bf16(h1[0].v, w2f[nt][0], z, 0, 0, 0);
        z = __builtin_amdgcn_mfma_f32_16x16x32_bf16(h1[1].v, w2f[nt][1], z, 0, 0, 0);
        acc[nt] = z;
    }

    float p[4];
    #pragma unroll
    for (int r = 0; r < 4; ++r) {
        float sum = 0.f;
        #pragma unroll
        for (int nt = 0; nt < 4; ++nt)
            sum += fmaxf(acc[nt][r] + b2l[nt], 0.f) * w3l[nt];
        p[r] = sum;
    }
    #pragma unroll
    for (int off = 1; off < 16; off <<= 1) {
        #pragma unroll
        for (int r = 0; r < 4; ++r)
            p[r] += __shfl_xor(p[r], off, 64);
    }
    if (col == 0) {
        #pragma unroll
        for (int r = 0; r < 4; ++r) {
            const int lr = q*4 + r;
            if (l0 + lr < cg) {
                const int keyr = fkey[s0 + lr];
                out[g*PPG + keyr] = p[r] + b3v;
            }
        }
    }
}

// ---------------------------------------------------------------------------
extern "C" void kernel_launch(void* const* d_in, const int* in_sizes, int n_in,
                              void* d_out, int out_size, void* d_ws, size_t ws_size,
                              hipStream_t stream)
{
    const float* x      = (const float*)d_in[0];
    const float* ea     = (const float*)d_in[1];
    const int*   eidx   = (const int*)  d_in[2];
    // d_in[3]=idx0, d_in[4]=idx1, d_in[5]=n  -- derivable, unused
    const float* W_atom = (const float*)d_in[6];
    const float* b_atom = (const float*)d_in[7];
    const float* W_bond = (const float*)d_in[8];
    const float* b_bond = (const float*)d_in[9];
    const float* W_node = (const float*)d_in[10];
    const float* b_node = (const float*)d_in[11];
    const float* W_edge = (const float*)d_in[12];
    const float* b_edge = (const float*)d_in[13];
    const float* W1     = (const float*)d_in[14];
    const float* b1     = (const float*)d_in[15];
    const float* W2     = (const float*)d_in[16];
    const float* b2     = (const float*)d_in[17];
    const float* W3     = (const float*)d_in[18];
    const float* b3     = (const float*)d_in[19];
    float* out = (float*)d_out;

    float* ws    = (float*)d_ws;
    float* Abuf  = ws;                       // [NN,64]
    float* Bbuf  = Abuf  + NN*HID;           // [NN,64]
    float* fsea  = Bbuf  + NN*HID;           // [NE,16]
    int*   fkey  = (int*)(fsea + NE*EF);     // [NE]
    int*   fcnt  = fkey + NE;                // [NE]
    int*   gcount= fcnt + NE;                // [BGR]
    float* wec   = (float*)(gcount + BGR);   // [16,64]
    float* biascg= wec + 16*64;              // [64]
    unsigned* gbm= (unsigned*)(biascg + 64); // [BGR,288]

    prep_kernel<<<64 + NN/12, 768, 0, stream>>>(
        x, W_atom, b_atom, W_node, b_node, W1, b1,
        ea, eidx, W_bond, b_bond, W_edge, b_edge,
        Abuf, Bbuf, fkey, fcnt, fsea, gcount, wec, biascg, gbm);
    pair_kernel<<<768 + NE/(FIXW*4), 256, 0, stream>>>(
        Abuf, Bbuf, fkey, fcnt, fsea, gcount, wec, biascg, gbm,
        W2, b2, W3, b3, out);
}